// Round 14
// baseline (130.738 us; speedup 1.0000x reference)
//
#include <hip/hip_runtime.h>

#define NCH 64
#define LAG 5
#define H0 32
#define H1 32
#define TIN 2048
#define TOUT 2044
#define NBATCH 16

#define XSTRIDE 72   // ushorts per staged X row (144 B, 16B-aligned rows)

typedef __attribute__((ext_vector_type(8))) short short8;    // 8 bf16 (4 VGPRs)
typedef __attribute__((ext_vector_type(4))) short short4v;   // 4 bf16 (2 VGPRs)
typedef __attribute__((ext_vector_type(4))) float f32x4;

__device__ __forceinline__ unsigned short f2bf(float f) {
    unsigned u = __float_as_uint(f);
    u += 0x7fffu + ((u >> 16) & 1u);     // RNE
    return (unsigned short)(u >> 16);
}

__device__ __forceinline__ unsigned pack2bf_relu(float a, float b) {
    unsigned ua = __float_as_uint(fmaxf(a, 0.0f));
    unsigned ub = __float_as_uint(fmaxf(b, 0.0f));
    ua += 0x7fffu + ((ua >> 16) & 1u);
    ub += 0x7fffu + ((ub >> 16) & 1u);
    return (ua >> 16) | (ub & 0xffff0000u);
}

__device__ __forceinline__ short4v pack4bf_relu(const f32x4& v) {
    union { short4v s; unsigned u[2]; } cv;
    cv.u[0] = pack2bf_relu(v[0], v[1]);
    cv.u[1] = pack2bf_relu(v[2], v[3]);
    return cv.s;
}

// ---- weights-only prep ----
__global__ __launch_bounds__(256) void prep_w(
    const float* __restrict__ W0, unsigned short* __restrict__ W0b,
    const float* __restrict__ W1, unsigned short* __restrict__ W1b,
    const float* __restrict__ W2, unsigned short* __restrict__ W2b)
{
    const int bx = blockIdx.x;
    if (bx < 512) {
        int j = bx * 256 + threadIdx.x;            // 131072 = 64n * 32h * 64c
        int nh = j >> 6, c = j & 63;
        const float* src = W0 + (size_t)j * LAG;
        unsigned short* dst = W0b + nh * 320 + c;
        #pragma unroll
        for (int l = 0; l < LAG; ++l) dst[l * 64] = f2bf(src[l]);
    } else if (bx < 544) {
        int i = ((bx - 512) * 256 + threadIdx.x) * 8;
        float4 a = *(const float4*)(W1 + i);
        float4 b = *(const float4*)(W1 + i + 4);
        unsigned long long v0 = (unsigned long long)f2bf(a.x)
                              | ((unsigned long long)f2bf(a.y) << 16)
                              | ((unsigned long long)f2bf(a.z) << 32)
                              | ((unsigned long long)f2bf(a.w) << 48);
        unsigned long long v1 = (unsigned long long)f2bf(b.x)
                              | ((unsigned long long)f2bf(b.y) << 16)
                              | ((unsigned long long)f2bf(b.z) << 32)
                              | ((unsigned long long)f2bf(b.w) << 48);
        *(unsigned long long*)(W1b + i)     = v0;
        *(unsigned long long*)(W1b + i + 4) = v1;
    } else {
        int i = threadIdx.x * 8;
        float4 a = *(const float4*)(W2 + i);
        float4 b = *(const float4*)(W2 + i + 4);
        unsigned long long v0 = (unsigned long long)f2bf(a.x)
                              | ((unsigned long long)f2bf(a.y) << 16)
                              | ((unsigned long long)f2bf(a.z) << 32)
                              | ((unsigned long long)f2bf(a.w) << 48);
        unsigned long long v1 = (unsigned long long)f2bf(b.x)
                              | ((unsigned long long)f2bf(b.y) << 16)
                              | ((unsigned long long)f2bf(b.z) << 32)
                              | ((unsigned long long)f2bf(b.w) << 48);
        *(unsigned long long*)(W2b + i)     = v0;
        *(unsigned long long*)(W2b + i + 4) = v1;
    }
}

// ---- main: block = 256-pos tile x 4 nets; wave = net; register-only L1/L2 ----
// Layer 0 transposed: D = W0(A-op) x Xwin^T(B-op) -> C[row=h][col=pos].
// R14: chunk-PAIR software pipeline -- layer0 of two chunks back-to-back
// (8 independent MFMA chains), then layers 1+2 of both (4 independent
// serial chains interleaved by the scheduler). acc = 32 AGPR; live ~150 < 170
// at (256,3) -> no spill. LDS 39,936 B (yt bf16).
__global__ __launch_bounds__(256, 3) void mlp_mfma(
    const float* __restrict__ X,
    const unsigned short* __restrict__ W0b,
    const unsigned short* __restrict__ W1b,
    const unsigned short* __restrict__ W2b,
    const float* __restrict__ b0, const float* __restrict__ b1,
    const float* __restrict__ b2, float* __restrict__ out)
{
    __shared__ __align__(16) unsigned short xs[260 * XSTRIDE];   // 37,440 B
    __shared__ __align__(8)  unsigned short yt[256][4];          //  2,048 B (bf16)

    const int tileid = blockIdx.x;
    const int ng     = blockIdx.y;
    const int b      = tileid >> 3;
    const int t0     = (tileid & 7) * 256;
    const int tid    = threadIdx.x;
    const int wave   = tid >> 6;
    const int lane   = tid & 63;
    const int quad   = lane >> 4;
    const int l15    = lane & 15;

    // ---- stage X tile: fp32 -> bf16 -> LDS ----
    const float* src = X + ((size_t)(b * TIN + t0)) * NCH;
    const int rows = (t0 == 1792) ? 256 : 260;
    for (int s = tid; s < rows * 16; s += 256) {
        int r = s >> 4, seg = s & 15;
        float4 x = *(const float4*)(src + s * 4);
        unsigned long long v = (unsigned long long)f2bf(x.x)
                             | ((unsigned long long)f2bf(x.y) << 16)
                             | ((unsigned long long)f2bf(x.z) << 32)
                             | ((unsigned long long)f2bf(x.w) << 48);
        *(unsigned long long*)&xs[r * XSTRIDE + seg * 4] = v;
    }
    __syncthreads();

    // ---- per-wave net: weight fragments (pre-repacked bf16), loaded once ----
    const int n = ng * 4 + wave;
    short8 B0[10][2];
    const unsigned short* wp0 = W0b + (n * H0 + l15) * (NCH * LAG) + quad * 8;
    #pragma unroll
    for (int ks = 0; ks < 10; ++ks) {
        B0[ks][0] = *(const short8*)(wp0 + ks * 32);
        B0[ks][1] = *(const short8*)(wp0 + 16 * (NCH * LAG) + ks * 32);
    }
    short4v A1[2][2];
    #pragma unroll
    for (int of = 0; of < 2; ++of)
        #pragma unroll
        for (int kf = 0; kf < 2; ++kf)
            A1[of][kf] = *(const short4v*)(W1b + (n * H1 + of * 16 + l15) * H0 + kf * 16 + quad * 4);
    short4v A2[2];
    #pragma unroll
    for (int kf = 0; kf < 2; ++kf)
        A2[kf] = *(const short4v*)(W2b + n * H1 + kf * 16 + quad * 4);
    f32x4 b0q[2], b1q[2];
    #pragma unroll
    for (int nf = 0; nf < 2; ++nf) b0q[nf] = *(const f32x4*)(b0 + (size_t)n * H0 + nf * 16 + quad * 4);
    #pragma unroll
    for (int of = 0; of < 2; ++of) b1q[of] = *(const f32x4*)(b1 + (size_t)n * H1 + of * 16 + quad * 4);
    const float b2s = b2[n];

    const int vmax = (t0 == 1792) ? 251 : 255;

    #pragma unroll 1
    for (int cp = 0; cp < 4; ++cp) {
        // two chunks: rows cp*64 .. cp*64+63; u = chunk-in-pair, mf = 16-row frag
        int rowoff[2][2];
        #pragma unroll
        for (int u = 0; u < 2; ++u)
            #pragma unroll
            for (int mf = 0; mf < 2; ++mf) {
                int i = cp * 64 + u * 32 + mf * 16 + l15;
                i = i < vmax ? i : vmax;
                rowoff[u][mf] = i * XSTRIDE + quad * 8;
            }

        // ---- layer 0 for BOTH chunks: 8 independent acc chains ----
        f32x4 acc[2][2][2];
        #pragma unroll
        for (int u = 0; u < 2; ++u)
            #pragma unroll
            for (int mf = 0; mf < 2; ++mf) {
                acc[u][mf][0] = b0q[0];
                acc[u][mf][1] = b0q[1];
            }
        #pragma unroll
        for (int ks = 0; ks < 10; ++ks) {
            const int xoff = (ks >> 1) * XSTRIDE + (ks & 1) * 32;
            #pragma unroll
            for (int u = 0; u < 2; ++u)
                #pragma unroll
                for (int mf = 0; mf < 2; ++mf) {
                    short8 Xf = *(const short8*)&xs[rowoff[u][mf] + xoff];
                    acc[u][mf][0] = __builtin_amdgcn_mfma_f32_16x16x32_bf16(B0[ks][0], Xf, acc[u][mf][0], 0, 0, 0);
                    acc[u][mf][1] = __builtin_amdgcn_mfma_f32_16x16x32_bf16(B0[ks][1], Xf, acc[u][mf][1], 0, 0, 0);
                }
        }

        // ---- layers 1+2 for BOTH chunks: 4 independent serial chains ----
        #pragma unroll
        for (int u = 0; u < 2; ++u)
            #pragma unroll
            for (int mf = 0; mf < 2; ++mf) {
                short4v Bh0 = pack4bf_relu(acc[u][mf][0]);   // h 0..15
                short4v Bh1 = pack4bf_relu(acc[u][mf][1]);   // h 16..31

                f32x4 D1[2] = { b1q[0], b1q[1] };
                D1[0] = __builtin_amdgcn_mfma_f32_16x16x16bf16_1k(A1[0][0], Bh0, D1[0], 0, 0, 0);
                D1[0] = __builtin_amdgcn_mfma_f32_16x16x16bf16_1k(A1[0][1], Bh1, D1[0], 0, 0, 0);
                D1[1] = __builtin_amdgcn_mfma_f32_16x16x16bf16_1k(A1[1][0], Bh0, D1[1], 0, 0, 0);
                D1[1] = __builtin_amdgcn_mfma_f32_16x16x16bf16_1k(A1[1][1], Bh1, D1[1], 0, 0, 0);

                short4v Bg0 = pack4bf_relu(D1[0]);           // o 0..15
                short4v Bg1 = pack4bf_relu(D1[1]);           // o 16..31

                f32x4 D2 = (f32x4){ b2s, b2s, b2s, b2s };
                D2 = __builtin_amdgcn_mfma_f32_16x16x16bf16_1k(A2[0], Bg0, D2, 0, 0, 0);
                D2 = __builtin_amdgcn_mfma_f32_16x16x16bf16_1k(A2[1], Bg1, D2, 0, 0, 0);

                if (quad == 0)
                    yt[cp * 64 + u * 32 + mf * 16 + l15][wave] = f2bf(D2[0]);
            }
    }
    __syncthreads();

    // ---- coalesced output: bf16 yt -> float4 per thread ----
    int t = t0 + tid;
    if (t < TOUT) {
        ushort4 v = *(const ushort4*)yt[tid];
        float4 o;
        o.x = __uint_as_float((unsigned)v.x << 16);
        o.y = __uint_as_float((unsigned)v.y << 16);
        o.z = __uint_as_float((unsigned)v.z << 16);
        o.w = __uint_as_float((unsigned)v.w << 16);
        *(float4*)&out[((size_t)(b * TOUT + t)) * NCH + ng * 4] = o;
    }
}

extern "C" void kernel_launch(void* const* d_in, const int* in_sizes, int n_in,
                              void* d_out, int out_size, void* d_ws, size_t ws_size,
                              hipStream_t stream)
{
    const float* X  = (const float*)d_in[0];
    const float* W0 = (const float*)d_in[1];
    const float* b0 = (const float*)d_in[2];
    const float* W1 = (const float*)d_in[3];
    const float* b1 = (const float*)d_in[4];
    const float* W2 = (const float*)d_in[5];
    const float* b2 = (const float*)d_in[6];
    float* out = (float*)d_out;

    unsigned short* W0b = (unsigned short*)d_ws;                    // 1,310,720 B
    unsigned short* W1b = (unsigned short*)((char*)d_ws + 1310720); //   131,072 B
    unsigned short* W2b = (unsigned short*)((char*)d_ws + 1441792); //     4,096 B

    prep_w<<<545, 256, 0, stream>>>(W0, W0b, W1, W1b, W2, W2b);
    mlp_mfma<<<dim3(128, 16), 256, 0, stream>>>(X, W0b, W1b, W2b, b0, b1, b2, out);
}

// Round 15
// 122.469 us; speedup vs baseline: 1.0675x; 1.0675x over previous
//
#include <hip/hip_runtime.h>

#define NCH 64
#define LAG 5
#define H0 32
#define H1 32
#define TIN 2048
#define TOUT 2044
#define NBATCH 16

#define XSTRIDE 72   // ushorts per staged X row (144 B = 128 data + 16 pad)

typedef __attribute__((ext_vector_type(8))) short short8;    // 8 bf16 (4 VGPRs)
typedef __attribute__((ext_vector_type(4))) short short4v;   // 4 bf16 (2 VGPRs)
typedef __attribute__((ext_vector_type(4))) float f32x4;

__device__ __forceinline__ unsigned short f2bf(float f) {
    unsigned u = __float_as_uint(f);
    u += 0x7fffu + ((u >> 16) & 1u);     // RNE
    return (unsigned short)(u >> 16);
}

__device__ __forceinline__ unsigned pack2bf_relu(float a, float b) {
    unsigned ua = __float_as_uint(fmaxf(a, 0.0f));
    unsigned ub = __float_as_uint(fmaxf(b, 0.0f));
    ua += 0x7fffu + ((ua >> 16) & 1u);
    ub += 0x7fffu + ((ub >> 16) & 1u);
    return (ua >> 16) | (ub & 0xffff0000u);
}

__device__ __forceinline__ short4v pack4bf_relu(const f32x4& v) {
    union { short4v s; unsigned u[2]; } cv;
    cv.u[0] = pack2bf_relu(v[0], v[1]);
    cv.u[1] = pack2bf_relu(v[2], v[3]);
    return cv.s;
}

// ---- fused prep: X -> padded bf16 image | W0 repack | W1 | W2 ----
// blocks [0,2048):    Xpad[b][t][72]: row = 128 B bf16 data + 16 B pad
// blocks [2048,2560): W0 [n][h][c][l] -> W0b[nh][k=l*64+c]
// blocks [2560,2592): W1 cast
// block  2592:        W2 cast
__global__ __launch_bounds__(256) void prep_all(
    const float* __restrict__ X,  unsigned short* __restrict__ Xpad,
    const float* __restrict__ W0, unsigned short* __restrict__ W0b,
    const float* __restrict__ W1, unsigned short* __restrict__ W1b,
    const float* __restrict__ W2, unsigned short* __restrict__ W2b)
{
    const int bx = blockIdx.x;
    if (bx < 2048) {
        int j = bx * 256 + threadIdx.x;        // 524,288 float4-groups
        int row = j >> 4, seg = j & 15;
        float4 x = *(const float4*)(X + (size_t)j * 4);
        unsigned long long v = (unsigned long long)f2bf(x.x)
                             | ((unsigned long long)f2bf(x.y) << 16)
                             | ((unsigned long long)f2bf(x.z) << 32)
                             | ((unsigned long long)f2bf(x.w) << 48);
        *(unsigned long long*)(Xpad + (size_t)row * XSTRIDE + seg * 4) = v;
    } else if (bx < 2560) {
        int j = (bx - 2048) * 256 + threadIdx.x;   // 131072 = 64n*32h*64c
        int nh = j >> 6, c = j & 63;
        const float* src = W0 + (size_t)j * LAG;
        unsigned short* dst = W0b + nh * 320 + c;
        #pragma unroll
        for (int l = 0; l < LAG; ++l) dst[l * 64] = f2bf(src[l]);
    } else if (bx < 2592) {
        int i = ((bx - 2560) * 256 + threadIdx.x) * 8;
        float4 a = *(const float4*)(W1 + i);
        float4 b = *(const float4*)(W1 + i + 4);
        unsigned long long v0 = (unsigned long long)f2bf(a.x)
                              | ((unsigned long long)f2bf(a.y) << 16)
                              | ((unsigned long long)f2bf(a.z) << 32)
                              | ((unsigned long long)f2bf(a.w) << 48);
        unsigned long long v1 = (unsigned long long)f2bf(b.x)
                              | ((unsigned long long)f2bf(b.y) << 16)
                              | ((unsigned long long)f2bf(b.z) << 32)
                              | ((unsigned long long)f2bf(b.w) << 48);
        *(unsigned long long*)(W1b + i)     = v0;
        *(unsigned long long*)(W1b + i + 4) = v1;
    } else {
        int i = threadIdx.x * 8;
        float4 a = *(const float4*)(W2 + i);
        float4 b = *(const float4*)(W2 + i + 4);
        unsigned long long v0 = (unsigned long long)f2bf(a.x)
                              | ((unsigned long long)f2bf(a.y) << 16)
                              | ((unsigned long long)f2bf(a.z) << 32)
                              | ((unsigned long long)f2bf(a.w) << 48);
        unsigned long long v1 = (unsigned long long)f2bf(b.x)
                              | ((unsigned long long)f2bf(b.y) << 16)
                              | ((unsigned long long)f2bf(b.z) << 32)
                              | ((unsigned long long)f2bf(b.w) << 48);
        *(unsigned long long*)(W2b + i)     = v0;
        *(unsigned long long*)(W2b + i + 4) = v1;
    }
}

// ---- main: block = 256-pos tile x 4 nets; wave = net; register-only L1/L2 ----
// Layer 0 transposed: D = W0(A-op) x Xwin^T(B-op) -> C[row=h][col=pos].
// Staging via global_load_lds (16B DMA, zero VALU): Xpad rows land at
// XSTRIDE=72 automatically because the pad is baked into the global image.
// LDS: xs 37,888 B (37 KB copied incl. 448 B slack) + yt 2,048 = 39,936 B.
__global__ __launch_bounds__(256, 3) void mlp_mfma(
    const unsigned short* __restrict__ Xpad,
    const unsigned short* __restrict__ W0b,
    const unsigned short* __restrict__ W1b,
    const unsigned short* __restrict__ W2b,
    const float* __restrict__ b0, const float* __restrict__ b1,
    const float* __restrict__ b2, float* __restrict__ out)
{
    __shared__ __align__(16) unsigned short xs[37 * 512];        // 37,888 B
    __shared__ __align__(8)  unsigned short yt[256][4];          //  2,048 B (bf16)

    const int tileid = blockIdx.x;
    const int ng     = blockIdx.y;
    const int b      = tileid >> 3;
    const int t0     = (tileid & 7) * 256;
    const int tid    = threadIdx.x;
    const int wave   = tid >> 6;
    const int lane   = tid & 63;
    const int quad   = lane >> 4;
    const int l15    = lane & 15;

    // ---- stage X tile: direct global->LDS DMA, 1 KB per instruction ----
    {
        const char* srcb = (const char*)(Xpad + (size_t)(b * TIN + t0) * XSTRIDE);
        #pragma unroll 1
        for (int i = wave; i < 37; i += 4) {
            __builtin_amdgcn_global_load_lds(
                (const __attribute__((address_space(1))) unsigned int*)(srcb + i * 1024 + lane * 16),
                (__attribute__((address_space(3))) unsigned int*)((char*)xs + i * 1024),
                16, 0, 0);
        }
    }

    // ---- per-wave net: weight fragments (pre-repacked bf16), loaded once ----
    const int n = ng * 4 + wave;
    short8 B0[10][2];
    const unsigned short* wp0 = W0b + (n * H0 + l15) * (NCH * LAG) + quad * 8;
    #pragma unroll
    for (int ks = 0; ks < 10; ++ks) {
        B0[ks][0] = *(const short8*)(wp0 + ks * 32);
        B0[ks][1] = *(const short8*)(wp0 + 16 * (NCH * LAG) + ks * 32);
    }
    short4v A1[2][2];
    #pragma unroll
    for (int of = 0; of < 2; ++of)
        #pragma unroll
        for (int kf = 0; kf < 2; ++kf)
            A1[of][kf] = *(const short4v*)(W1b + (n * H1 + of * 16 + l15) * H0 + kf * 16 + quad * 4);
    short4v A2[2];
    #pragma unroll
    for (int kf = 0; kf < 2; ++kf)
        A2[kf] = *(const short4v*)(W2b + n * H1 + kf * 16 + quad * 4);
    f32x4 b0q[2], b1q[2];
    #pragma unroll
    for (int nf = 0; nf < 2; ++nf) b0q[nf] = *(const f32x4*)(b0 + (size_t)n * H0 + nf * 16 + quad * 4);
    #pragma unroll
    for (int of = 0; of < 2; ++of) b1q[of] = *(const f32x4*)(b1 + (size_t)n * H1 + of * 16 + quad * 4);
    const float b2s = b2[n];

    __syncthreads();   // drains global_load_lds (vmcnt) + weight loads

    const int vmax = (t0 == 1792) ? 251 : 255;

    #pragma unroll 1
    for (int chunk = 0; chunk < 8; ++chunk) {
        int rowoff[2];
        #pragma unroll
        for (int mf = 0; mf < 2; ++mf) {
            int i = chunk * 32 + mf * 16 + l15;
            i = i < vmax ? i : vmax;
            rowoff[mf] = i * XSTRIDE + quad * 8;
        }

        // ---- layer 0 (transposed): acc[mf][nf] = C[row=h][col=pos] ----
        f32x4 acc[2][2];
        #pragma unroll
        for (int mf = 0; mf < 2; ++mf) {
            acc[mf][0] = b0q[0];
            acc[mf][1] = b0q[1];
        }
        #pragma unroll
        for (int ks = 0; ks < 10; ++ks) {
            const int xoff = (ks >> 1) * XSTRIDE + (ks & 1) * 32;
            #pragma unroll
            for (int mf = 0; mf < 2; ++mf) {
                short8 Xf = *(const short8*)&xs[rowoff[mf] + xoff];   // B-op: n=pos
                acc[mf][0] = __builtin_amdgcn_mfma_f32_16x16x32_bf16(B0[ks][0], Xf, acc[mf][0], 0, 0, 0);
                acc[mf][1] = __builtin_amdgcn_mfma_f32_16x16x32_bf16(B0[ks][1], Xf, acc[mf][1], 0, 0, 0);
            }
        }

        // ---- layers 1+2: register-only ----
        #pragma unroll
        for (int mf = 0; mf < 2; ++mf) {
            short4v Bh0 = pack4bf_relu(acc[mf][0]);   // h 0..15
            short4v Bh1 = pack4bf_relu(acc[mf][1]);   // h 16..31

            f32x4 D1[2] = { b1q[0], b1q[1] };
            D1[0] = __builtin_amdgcn_mfma_f32_16x16x16bf16_1k(A1[0][0], Bh0, D1[0], 0, 0, 0);
            D1[0] = __builtin_amdgcn_mfma_f32_16x16x16bf16_1k(A1[0][1], Bh1, D1[0], 0, 0, 0);
            D1[1] = __builtin_amdgcn_mfma_f32_16x16x16bf16_1k(A1[1][0], Bh0, D1[1], 0, 0, 0);
            D1[1] = __builtin_amdgcn_mfma_f32_16x16x16bf16_1k(A1[1][1], Bh1, D1[1], 0, 0, 0);

            short4v Bg0 = pack4bf_relu(D1[0]);        // o 0..15
            short4v Bg1 = pack4bf_relu(D1[1]);        // o 16..31

            f32x4 D2 = (f32x4){ b2s, b2s, b2s, b2s };
            D2 = __builtin_amdgcn_mfma_f32_16x16x16bf16_1k(A2[0], Bg0, D2, 0, 0, 0);
            D2 = __builtin_amdgcn_mfma_f32_16x16x16bf16_1k(A2[1], Bg1, D2, 0, 0, 0);

            if (quad == 0)
                yt[chunk * 32 + mf * 16 + l15][wave] = f2bf(D2[0]);
        }
    }
    __syncthreads();

    // ---- coalesced output: bf16 yt -> float4 per thread ----
    int t = t0 + tid;
    if (t < TOUT) {
        ushort4 v = *(const ushort4*)yt[tid];
        float4 o;
        o.x = __uint_as_float((unsigned)v.x << 16);
        o.y = __uint_as_float((unsigned)v.y << 16);
        o.z = __uint_as_float((unsigned)v.z << 16);
        o.w = __uint_as_float((unsigned)v.w << 16);
        *(float4*)&out[((size_t)(b * TOUT + t)) * NCH + ng * 4] = o;
    }
}

extern "C" void kernel_launch(void* const* d_in, const int* in_sizes, int n_in,
                              void* d_out, int out_size, void* d_ws, size_t ws_size,
                              hipStream_t stream)
{
    const float* X  = (const float*)d_in[0];
    const float* W0 = (const float*)d_in[1];
    const float* b0 = (const float*)d_in[2];
    const float* W1 = (const float*)d_in[3];
    const float* b1 = (const float*)d_in[4];
    const float* W2 = (const float*)d_in[5];
    const float* b2 = (const float*)d_in[6];
    float* out = (float*)d_out;

    // ws layout: Xpad 4,718,592 B (+8,192 cushion for tail over-copy), then weights
    unsigned short* Xpad = (unsigned short*)d_ws;
    unsigned short* W0b  = (unsigned short*)((char*)d_ws + 4726784);   // 1,310,720 B
    unsigned short* W1b  = (unsigned short*)((char*)d_ws + 6037504);   //   131,072 B
    unsigned short* W2b  = (unsigned short*)((char*)d_ws + 6168576);   //     4,096 B

    prep_all<<<2593, 256, 0, stream>>>(X, Xpad, W0, W0b, W1, W1b, W2, W2b);
    mlp_mfma<<<dim3(128, 16), 256, 0, stream>>>(Xpad, W0b, W1b, W2b, b0, b1, b2, out);
}

// Round 17
// 119.911 us; speedup vs baseline: 1.0903x; 1.0213x over previous
//
#include <hip/hip_runtime.h>

#define NCH 64
#define LAG 5
#define H0 32
#define H1 32
#define TIN 2048
#define TOUT 2044
#define NBATCH 16

#define XSTRIDE 72   // ushorts per staged X row (144 B = 128 data + 16 pad)

typedef __attribute__((ext_vector_type(8))) short short8;    // 8 bf16 (4 VGPRs)
typedef __attribute__((ext_vector_type(4))) short short4v;   // 4 bf16 (2 VGPRs)
typedef __attribute__((ext_vector_type(4))) float f32x4;

__device__ __forceinline__ unsigned short f2bf(float f) {
    unsigned u = __float_as_uint(f);
    u += 0x7fffu + ((u >> 16) & 1u);     // RNE
    return (unsigned short)(u >> 16);
}

// ReLU + round-half-up bf16 pack: inputs are >= 0 after fmax, so u+0x8000
// then hi16 is round-half-up (max err 0.5 ulp, same bound as RNE).
// One v_perm_b32 extracts both hi16s: dst = [ua.b2, ua.b3, ub.b2, ub.b3].
__device__ __forceinline__ unsigned pack2bf_relu(float a, float b) {
    unsigned ua = __float_as_uint(fmaxf(a, 0.0f)) + 0x8000u;
    unsigned ub = __float_as_uint(fmaxf(b, 0.0f)) + 0x8000u;
    return __builtin_amdgcn_perm(ub, ua, 0x07060302u);   // src0=ub (idx 4-7), src1=ua (idx 0-3)
}

__device__ __forceinline__ short4v pack4bf_relu(const f32x4& v) {
    union { short4v s; unsigned u[2]; } cv;
    cv.u[0] = pack2bf_relu(v[0], v[1]);
    cv.u[1] = pack2bf_relu(v[2], v[3]);
    return cv.s;
}

// ---- fused prep: X -> padded bf16 image | W0 repack | W1 | W2 ----
__global__ __launch_bounds__(256) void prep_all(
    const float* __restrict__ X,  unsigned short* __restrict__ Xpad,
    const float* __restrict__ W0, unsigned short* __restrict__ W0b,
    const float* __restrict__ W1, unsigned short* __restrict__ W1b,
    const float* __restrict__ W2, unsigned short* __restrict__ W2b)
{
    const int bx = blockIdx.x;
    if (bx < 2048) {
        int j = bx * 256 + threadIdx.x;        // 524,288 float4-groups
        int row = j >> 4, seg = j & 15;
        float4 x = *(const float4*)(X + (size_t)j * 4);
        unsigned long long v = (unsigned long long)f2bf(x.x)
                             | ((unsigned long long)f2bf(x.y) << 16)
                             | ((unsigned long long)f2bf(x.z) << 32)
                             | ((unsigned long long)f2bf(x.w) << 48);
        *(unsigned long long*)(Xpad + (size_t)row * XSTRIDE + seg * 4) = v;
    } else if (bx < 2560) {
        int j = (bx - 2048) * 256 + threadIdx.x;   // 131072 = 64n*32h*64c
        int nh = j >> 6, c = j & 63;
        const float* src = W0 + (size_t)j * LAG;
        unsigned short* dst = W0b + nh * 320 + c;
        #pragma unroll
        for (int l = 0; l < LAG; ++l) dst[l * 64] = f2bf(src[l]);
    } else if (bx < 2592) {
        int i = ((bx - 2560) * 256 + threadIdx.x) * 8;
        float4 a = *(const float4*)(W1 + i);
        float4 b = *(const float4*)(W1 + i + 4);
        unsigned long long v0 = (unsigned long long)f2bf(a.x)
                              | ((unsigned long long)f2bf(a.y) << 16)
                              | ((unsigned long long)f2bf(a.z) << 32)
                              | ((unsigned long long)f2bf(a.w) << 48);
        unsigned long long v1 = (unsigned long long)f2bf(b.x)
                              | ((unsigned long long)f2bf(b.y) << 16)
                              | ((unsigned long long)f2bf(b.z) << 32)
                              | ((unsigned long long)f2bf(b.w) << 48);
        *(unsigned long long*)(W1b + i)     = v0;
        *(unsigned long long*)(W1b + i + 4) = v1;
    } else {
        int i = threadIdx.x * 8;
        float4 a = *(const float4*)(W2 + i);
        float4 b = *(const float4*)(W2 + i + 4);
        unsigned long long v0 = (unsigned long long)f2bf(a.x)
                              | ((unsigned long long)f2bf(a.y) << 16)
                              | ((unsigned long long)f2bf(a.z) << 32)
                              | ((unsigned long long)f2bf(a.w) << 48);
        unsigned long long v1 = (unsigned long long)f2bf(b.x)
                              | ((unsigned long long)f2bf(b.y) << 16)
                              | ((unsigned long long)f2bf(b.z) << 32)
                              | ((unsigned long long)f2bf(b.w) << 48);
        *(unsigned long long*)(W2b + i)     = v0;
        *(unsigned long long*)(W2b + i + 4) = v1;
    }
}

// ---- main: block = 256-pos tile x 4 nets; wave = net; register-only L1/L2 ----
// Layer 0 transposed: D = W0(A-op) x Xwin^T(B-op) -> C[row=h][col=pos].
// Staging via global_load_lds (16B DMA, zero VALU); bf16 pack via
// add-0x8000 + v_perm_b32 (5 VALU ops per pair vs ~13 manual RNE).
__global__ __launch_bounds__(256, 3) void mlp_mfma(
    const unsigned short* __restrict__ Xpad,
    const unsigned short* __restrict__ W0b,
    const unsigned short* __restrict__ W1b,
    const unsigned short* __restrict__ W2b,
    const float* __restrict__ b0, const float* __restrict__ b1,
    const float* __restrict__ b2, float* __restrict__ out)
{
    __shared__ __align__(16) unsigned short xs[37 * 512];        // 37,888 B
    __shared__ __align__(8)  unsigned short yt[256][4];          //  2,048 B (bf16)

    const int tileid = blockIdx.x;
    const int ng     = blockIdx.y;
    const int b      = tileid >> 3;
    const int t0     = (tileid & 7) * 256;
    const int tid    = threadIdx.x;
    const int wave   = tid >> 6;
    const int lane   = tid & 63;
    const int quad   = lane >> 4;
    const int l15    = lane & 15;

    // ---- stage X tile: direct global->LDS DMA, 1 KB per instruction ----
    {
        const char* srcb = (const char*)(Xpad + (size_t)(b * TIN + t0) * XSTRIDE);
        #pragma unroll 1
        for (int i = wave; i < 37; i += 4) {
            __builtin_amdgcn_global_load_lds(
                (const __attribute__((address_space(1))) unsigned int*)(srcb + i * 1024 + lane * 16),
                (__attribute__((address_space(3))) unsigned int*)((char*)xs + i * 1024),
                16, 0, 0);
        }
    }

    // ---- per-wave net: weight fragments (pre-repacked bf16), loaded once ----
    const int n = ng * 4 + wave;
    short8 B0[10][2];
    const unsigned short* wp0 = W0b + (n * H0 + l15) * (NCH * LAG) + quad * 8;
    #pragma unroll
    for (int ks = 0; ks < 10; ++ks) {
        B0[ks][0] = *(const short8*)(wp0 + ks * 32);
        B0[ks][1] = *(const short8*)(wp0 + 16 * (NCH * LAG) + ks * 32);
    }
    short4v A1[2][2];
    #pragma unroll
    for (int of = 0; of < 2; ++of)
        #pragma unroll
        for (int kf = 0; kf < 2; ++kf)
            A1[of][kf] = *(const short4v*)(W1b + (n * H1 + of * 16 + l15) * H0 + kf * 16 + quad * 4);
    short4v A2[2];
    #pragma unroll
    for (int kf = 0; kf < 2; ++kf)
        A2[kf] = *(const short4v*)(W2b + n * H1 + kf * 16 + quad * 4);
    f32x4 b0q[2], b1q[2];
    #pragma unroll
    for (int nf = 0; nf < 2; ++nf) b0q[nf] = *(const f32x4*)(b0 + (size_t)n * H0 + nf * 16 + quad * 4);
    #pragma unroll
    for (int of = 0; of < 2; ++of) b1q[of] = *(const f32x4*)(b1 + (size_t)n * H1 + of * 16 + quad * 4);
    const float b2s = b2[n];

    __syncthreads();   // drains global_load_lds (vmcnt) + weight loads

    const int vmax = (t0 == 1792) ? 251 : 255;

    #pragma unroll 1
    for (int chunk = 0; chunk < 8; ++chunk) {
        int rowoff[2];
        #pragma unroll
        for (int mf = 0; mf < 2; ++mf) {
            int i = chunk * 32 + mf * 16 + l15;
            i = i < vmax ? i : vmax;
            rowoff[mf] = i * XSTRIDE + quad * 8;
        }

        // ---- layer 0 (transposed): acc[mf][nf] = C[row=h][col=pos] ----
        f32x4 acc[2][2];
        #pragma unroll
        for (int mf = 0; mf < 2; ++mf) {
            acc[mf][0] = b0q[0];
            acc[mf][1] = b0q[1];
        }
        #pragma unroll
        for (int ks = 0; ks < 10; ++ks) {
            const int xoff = (ks >> 1) * XSTRIDE + (ks & 1) * 32;
            #pragma unroll
            for (int mf = 0; mf < 2; ++mf) {
                short8 Xf = *(const short8*)&xs[rowoff[mf] + xoff];   // B-op: n=pos
                acc[mf][0] = __builtin_amdgcn_mfma_f32_16x16x32_bf16(B0[ks][0], Xf, acc[mf][0], 0, 0, 0);
                acc[mf][1] = __builtin_amdgcn_mfma_f32_16x16x32_bf16(B0[ks][1], Xf, acc[mf][1], 0, 0, 0);
            }
        }

        // ---- layers 1+2: register-only ----
        #pragma unroll
        for (int mf = 0; mf < 2; ++mf) {
            short4v Bh0 = pack4bf_relu(acc[mf][0]);   // h 0..15
            short4v Bh1 = pack4bf_relu(acc[mf][1]);   // h 16..31

            f32x4 D1[2] = { b1q[0], b1q[1] };
            D1[0] = __builtin_amdgcn_mfma_f32_16x16x16bf16_1k(A1[0][0], Bh0, D1[0], 0, 0, 0);
            D1[0] = __builtin_amdgcn_mfma_f32_16x16x16bf16_1k(A1[0][1], Bh1, D1[0], 0, 0, 0);
            D1[1] = __builtin_amdgcn_mfma_f32_16x16x16bf16_1k(A1[1][0], Bh0, D1[1], 0, 0, 0);
            D1[1] = __builtin_amdgcn_mfma_f32_16x16x16bf16_1k(A1[1][1], Bh1, D1[1], 0, 0, 0);

            short4v Bg0 = pack4bf_relu(D1[0]);        // o 0..15
            short4v Bg1 = pack4bf_relu(D1[1]);        // o 16..31

            f32x4 D2 = (f32x4){ b2s, b2s, b2s, b2s };
            D2 = __builtin_amdgcn_mfma_f32_16x16x16bf16_1k(A2[0], Bg0, D2, 0, 0, 0);
            D2 = __builtin_amdgcn_mfma_f32_16x16x16bf16_1k(A2[1], Bg1, D2, 0, 0, 0);

            if (quad == 0)
                yt[chunk * 32 + mf * 16 + l15][wave] = f2bf(D2[0]);
        }
    }
    __syncthreads();

    // ---- coalesced output: bf16 yt -> float4 per thread ----
    int t = t0 + tid;
    if (t < TOUT) {
        ushort4 v = *(const ushort4*)yt[tid];
        float4 o;
        o.x = __uint_as_float((unsigned)v.x << 16);
        o.y = __uint_as_float((unsigned)v.y << 16);
        o.z = __uint_as_float((unsigned)v.z << 16);
        o.w = __uint_as_float((unsigned)v.w << 16);
        *(float4*)&out[((size_t)(b * TOUT + t)) * NCH + ng * 4] = o;
    }
}

extern "C" void kernel_launch(void* const* d_in, const int* in_sizes, int n_in,
                              void* d_out, int out_size, void* d_ws, size_t ws_size,
                              hipStream_t stream)
{
    const float* X  = (const float*)d_in[0];
    const float* W0 = (const float*)d_in[1];
    const float* b0 = (const float*)d_in[2];
    const float* W1 = (const float*)d_in[3];
    const float* b1 = (const float*)d_in[4];
    const float* W2 = (const float*)d_in[5];
    const float* b2 = (const float*)d_in[6];
    float* out = (float*)d_out;

    // ws layout: Xpad 4,718,592 B (+8,192 cushion for tail over-copy), then weights
    unsigned short* Xpad = (unsigned short*)d_ws;
    unsigned short* W0b  = (unsigned short*)((char*)d_ws + 4726784);   // 1,310,720 B
    unsigned short* W1b  = (unsigned short*)((char*)d_ws + 6037504);   //   131,072 B
    unsigned short* W2b  = (unsigned short*)((char*)d_ws + 6168576);   //     4,096 B

    prep_all<<<2593, 256, 0, stream>>>(X, Xpad, W0, W0b, W1, W1b, W2, W2b);
    mlp_mfma<<<dim3(128, 16), 256, 0, stream>>>(Xpad, W0b, W1b, W2b, b0, b1, b2, out);
}